// Round 1
// baseline (8127.500 us; speedup 1.0000x reference)
//
#include <hip/hip_runtime.h>

typedef unsigned short ushort_t;
typedef __attribute__((ext_vector_type(8))) short bf16x8;
typedef __attribute__((ext_vector_type(4))) float f32x4;

__device__ __forceinline__ ushort_t f2bf(float f) {
  unsigned u = __float_as_uint(f);
  unsigned r = (u + 0x7fffu + ((u >> 16) & 1u)) >> 16;
  return (ushort_t)r;
}
__device__ __forceinline__ float bf2f(ushort_t h) {
  return __uint_as_float(((unsigned)h) << 16);
}

#if defined(__has_builtin)
#if __has_builtin(__builtin_amdgcn_global_load_lds)
#define USE_GLL 1
#endif
#endif
#ifndef USE_GLL
#define USE_GLL 0
#endif

__device__ __forceinline__ void gll16(const void* g, void* l) {
#if USE_GLL
  __builtin_amdgcn_global_load_lds(
      (const __attribute__((address_space(1))) unsigned int*)g,
      (__attribute__((address_space(3))) unsigned int*)l, 16, 0, 0);
#endif
}

// ---------------- fp32 -> bf16 convert (grid-stride, float4) ----------------
__global__ void k_cvt_bf16(const float* __restrict__ in, ushort_t* __restrict__ out, int n4) {
  int i = blockIdx.x * blockDim.x + threadIdx.x;
  int stride = gridDim.x * blockDim.x;
  for (; i < n4; i += stride) {
    float4 v = reinterpret_cast<const float4*>(in)[i];
    ushort4 o;
    o.x = f2bf(v.x); o.y = f2bf(v.y); o.z = f2bf(v.z); o.w = f2bf(v.w);
    reinterpret_cast<ushort4*>(out)[i] = o;
  }
}

// ------------- 512x512 transpose + convert: out[n][k] = bf16(in[k][n]) ------
__global__ __launch_bounds__(256) void k_transpose_cvt(const float* __restrict__ in,
                                                       ushort_t* __restrict__ out) {
  __shared__ float tile[32][33];
  int bx = blockIdx.x & 15, by = blockIdx.x >> 4;
  int tx = threadIdx.x & 31, ty = threadIdx.x >> 5;  // ty in 0..7
#pragma unroll
  for (int i = 0; i < 4; ++i)
    tile[ty + i * 8][tx] = in[(size_t)(by * 32 + ty + i * 8) * 512 + bx * 32 + tx];
  __syncthreads();
#pragma unroll
  for (int i = 0; i < 4; ++i)
    out[(size_t)(bx * 32 + ty + i * 8) * 512 + by * 32 + tx] = f2bf(tile[tx][ty + i * 8]);
}

// ---------------- bf16 MFMA GEMM: C[M][N] = A[M][K] * Bt[N][K]^T + bias -----
#define BM 128
#define BN 128
#define BK 32

template <int OUT_BF16>
__global__ __launch_bounds__(256, 2) void k_gemm(const ushort_t* __restrict__ A,
                                                 const ushort_t* __restrict__ Bt,
                                                 const float* __restrict__ bias,
                                                 void* __restrict__ Cout,
                                                 int M, int N, int K) {
  __shared__ __align__(16) ushort_t As[2][BM][BK];
  __shared__ __align__(16) ushort_t Bs[2][BN][BK];

  const int tid = threadIdx.x;
  const int w = tid >> 6;       // wave 0..3
  const int l = tid & 63;       // lane
  const int nbn = N / BN;
  const int bm0 = (int)(blockIdx.x / nbn) * BM;
  const int bn0 = (int)(blockIdx.x % nbn) * BN;
  const int wm = w >> 1, wn = w & 1;

  auto stage = [&](int buf, int kt) {
#pragma unroll
    for (int c = 0; c < 2; ++c) {
      const int row = c * 64 + w * 16 + (l >> 2);
      const int ke = kt + (l & 3) * 8;
#if USE_GLL
      gll16(A + (size_t)(bm0 + row) * K + ke, &As[buf][c * 64 + w * 16][0]);
      gll16(Bt + (size_t)(bn0 + row) * K + ke, &Bs[buf][c * 64 + w * 16][0]);
#else
      *(bf16x8*)&As[buf][row][(l & 3) * 8] = *(const bf16x8*)(A + (size_t)(bm0 + row) * K + ke);
      *(bf16x8*)&Bs[buf][row][(l & 3) * 8] = *(const bf16x8*)(Bt + (size_t)(bn0 + row) * K + ke);
#endif
    }
  };

  f32x4 acc[4][4] = {};
  const int nkt = K / BK;
  stage(0, 0);
  int cur = 0;
  for (int kt = 0; kt < nkt; ++kt) {
    __syncthreads();  // drains vmcnt: staged data for buf `cur` is visible to all
    if (kt + 1 < nkt) stage(cur ^ 1, (kt + 1) * BK);
    bf16x8 af[4], bfr[4];
#pragma unroll
    for (int m = 0; m < 4; ++m)
      af[m] = *(const bf16x8*)&As[cur][wm * 64 + m * 16 + (l & 15)][(l >> 4) * 8];
#pragma unroll
    for (int n = 0; n < 4; ++n)
      bfr[n] = *(const bf16x8*)&Bs[cur][wn * 64 + n * 16 + (l & 15)][(l >> 4) * 8];
#pragma unroll
    for (int m = 0; m < 4; ++m)
#pragma unroll
      for (int n = 0; n < 4; ++n)
        acc[m][n] = __builtin_amdgcn_mfma_f32_16x16x32_bf16(af[m], bfr[n], acc[m][n], 0, 0, 0);
    cur ^= 1;
  }

  // Epilogue. C/D layout: col = lane&15, row = (lane>>4)*4 + j  [HW-verified]
  const int r0 = bm0 + wm * 64, c0 = bn0 + wn * 64;
#pragma unroll
  for (int n = 0; n < 4; ++n) {
    const int cc = c0 + n * 16 + (l & 15);
    const float bv = bias[cc];
#pragma unroll
    for (int m = 0; m < 4; ++m) {
      const int rr = r0 + m * 16 + ((l >> 4) << 2);
#pragma unroll
      for (int j = 0; j < 4; ++j) {
        float v = acc[m][n][j] + bv;
        if (OUT_BF16)
          ((ushort_t*)Cout)[(size_t)(rr + j) * N + cc] = f2bf(v);
        else
          ((float*)Cout)[(size_t)(rr + j) * N + cc] = v;
      }
    }
  }
}

// ---------------- RNN scan: one WG per batch, h in LDS, bf16 W_hh -----------
__global__ __launch_bounds__(512) void k_scan(const ushort_t* __restrict__ xw,   // [B][T][512] bf16
                                              const ushort_t* __restrict__ Whh,  // [512][512] bf16
                                              ushort_t* __restrict__ hs,         // [B][T][512] bf16
                                              float* __restrict__ h_last,        // [B][512] f32
                                              int T) {
  const int b = blockIdx.x;
  const int j = threadIdx.x;
  __shared__ float h[512];
  h[j] = 0.0f;
  __syncthreads();

  const ushort_t* xwp = xw + (size_t)b * T * 512 + j;
  ushort_t* hsp = hs + (size_t)b * T * 512 + j;

  for (int t = 0; t < T; ++t) {
    float a0 = bf2f(*xwp), a1 = 0.f, a2 = 0.f, a3 = 0.f;
    const ushort_t* wp = Whh + j;
#pragma unroll 4
    for (int k = 0; k < 512; k += 4) {
      float4 h4 = *(const float4*)&h[k];
      a0 += h4.x * bf2f(wp[0]);
      a1 += h4.y * bf2f(wp[512]);
      a2 += h4.z * bf2f(wp[1024]);
      a3 += h4.w * bf2f(wp[1536]);
      wp += 2048;
    }
    float hn = tanhf((a0 + a1) + (a2 + a3));
    __syncthreads();   // everyone done reading h
    h[j] = hn;
    *hsp = f2bf(hn);
    xwp += 512;
    hsp += 512;
    __syncthreads();   // h fully updated
  }
  h_last[(size_t)b * 512 + j] = h[j];
}

// ---------------------------------------------------------------------------
extern "C" void kernel_launch(void* const* d_in, const int* in_sizes, int n_in,
                              void* d_out, int out_size, void* d_ws, size_t ws_size,
                              hipStream_t stream) {
  const float* x    = (const float*)d_in[0];  // [64][1024][512]
  const float* W_xh = (const float*)d_in[1];  // [512][512]
  const float* b_h  = (const float*)d_in[2];  // [512]
  const float* W_hh = (const float*)d_in[3];  // [512][512]
  const float* W_o  = (const float*)d_in[4];  // [512][512]
  const float* b_o  = (const float*)d_in[5];  // [512]
  float* out = (float*)d_out;                 // logits [64][1024][512] ++ h_last [64][512]

  const size_t XWN = (size_t)64 * 1024 * 512;       // 33,554,432 elems
  char* ws = (char*)d_ws;
  ushort_t* xbf   = (ushort_t*)(ws);                         // 64 MiB (x bf16, later reused as hs)
  ushort_t* xwbf  = (ushort_t*)(ws + XWN * 2);               // 64 MiB (xW bf16)
  ushort_t* WxhT  = (ushort_t*)(ws + XWN * 4);               // 512 KiB
  ushort_t* WoT   = (ushort_t*)(ws + XWN * 4 + 524288);      // 512 KiB
  ushort_t* WhhB  = (ushort_t*)(ws + XWN * 4 + 1048576);     // 512 KiB

  // prep: converts + transposes
  k_cvt_bf16<<<4096, 256, 0, stream>>>(x, xbf, (int)(XWN / 4));
  k_cvt_bf16<<<64, 256, 0, stream>>>(W_hh, WhhB, 512 * 512 / 4);
  k_transpose_cvt<<<256, 256, 0, stream>>>(W_xh, WxhT);
  k_transpose_cvt<<<256, 256, 0, stream>>>(W_o, WoT);

  // xW = x @ W_xh + b_h   (bf16 out)
  k_gemm<1><<<2048, 256, 0, stream>>>(xbf, WxhT, b_h, xwbf, 65536, 512, 512);

  // sequential scan; writes hs (bf16, reusing x's buffer) and h_last (f32)
  k_scan<<<64, 512, 0, stream>>>(xwbf, WhhB, xbf, out + XWN, 1024);

  // logits = hs @ W_o + b_o   (f32 out)
  k_gemm<0><<<2048, 256, 0, stream>>>(xbf, WoT, b_o, out, 65536, 512, 512);
}